// Round 1
// baseline (605.547 us; speedup 1.0000x reference)
//
#include <hip/hip_runtime.h>
#include <stdint.h>

#define IN_F  4096
#define OUT_F 4096
#define ROWS  8192
#define QDIM  1024

typedef __attribute__((ext_vector_type(8))) short bf16x8;
typedef __attribute__((ext_vector_type(4))) float f32x4;
typedef __attribute__((ext_vector_type(8))) unsigned short u16x8;

// round-to-nearest-even f32 -> bf16 (explicit, so we don't depend on header rounding mode)
__device__ __forceinline__ unsigned short f2bf(float f) {
  union { float f; unsigned int u; } v; v.f = f;
  unsigned int u = v.u;
  u += 0x7FFFu + ((u >> 16) & 1u);
  return (unsigned short)(u >> 16);
}

// ---------------- prepass 1: x fp32 -> bf16 (8 elems / thread) ----------------
__global__ void cvt_x_kernel(const float* __restrict__ x, unsigned short* __restrict__ xb) {
  const size_t t = (size_t)blockIdx.x * 256 + threadIdx.x;
  const float4* x4 = reinterpret_cast<const float4*>(x);
  float4 a = x4[2 * t];
  float4 b = x4[2 * t + 1];
  u16x8 o;
  o[0] = f2bf(a.x); o[1] = f2bf(a.y); o[2] = f2bf(a.z); o[3] = f2bf(a.w);
  o[4] = f2bf(b.x); o[5] = f2bf(b.y); o[6] = f2bf(b.z); o[7] = f2bf(b.w);
  *reinterpret_cast<u16x8*>(xb + 8 * t) = o;
}

// ---------------- prepass 2: build Wt (bf16, [n][k] = W^T) with signs folded ----------------
// W row-block rq (k), col-block cq (n):
//   cq0: [ r, -i, -j, -k]   cq1: [ i, r, -k, j]   cq2: [ j, k, r, -i]   cq3: [ k, -j, i, r]
__global__ void build_wt_kernel(const float* __restrict__ rw, const float* __restrict__ iw,
                                const float* __restrict__ jw, const float* __restrict__ kw,
                                unsigned short* __restrict__ wt) {
  __shared__ float tile[64][65];                 // +1 pad: conflict-free transpose
  const int bid = blockIdx.x;
  const int tn = bid >> 6;                       // n-tile 0..63
  const int tk = bid & 63;                       // k-tile 0..63
  const int n0 = tn << 6, k0 = tk << 6;
  const int cq = n0 >> 10, rq = k0 >> 10;
  const int   it[16] = {0,1,2,3, 1,0,3,2, 2,3,0,1, 3,2,1,0};
  const float st[16] = { 1.f, 1.f, 1.f, 1.f,
                        -1.f, 1.f, 1.f,-1.f,
                        -1.f,-1.f, 1.f, 1.f,
                        -1.f, 1.f,-1.f, 1.f};
  const float* srcs[4] = {rw, iw, jw, kw};
  const float* src = srcs[it[rq * 4 + cq]];
  const float sgn  = st[rq * 4 + cq];
  const int tx = threadIdx.x & 63;
  const int ty = threadIdx.x >> 6;
  const int ks = k0 & 1023, ns = n0 & 1023;
  #pragma unroll
  for (int r = ty; r < 64; r += 4)               // coalesced read of weight quadrant
    tile[r][tx] = src[(size_t)(ks + r) * QDIM + ns + tx] * sgn;
  __syncthreads();
  #pragma unroll
  for (int r = ty; r < 64; r += 4)               // coalesced write of Wt (contiguous in k)
    wt[(size_t)(n0 + r) * IN_F + k0 + tx] = f2bf(tile[tx][r]);
}

// ---------------- GEMM: C[M][N] = A[M][K](bf16) * Wt[N][K]^T + bias ----------------
#define BM 128
#define BN 128
#define BK 32
#define NKSTEP (IN_F / BK)   // 128

#define GLD(g, l) __builtin_amdgcn_global_load_lds(                         \
    (const __attribute__((address_space(1))) void*)(g),                     \
    (__attribute__((address_space(3))) void*)(l), 16, 0, 0)

__global__ __launch_bounds__(256, 2) void qgemm_kernel(
    const unsigned short* __restrict__ A,    // [ROWS][IN_F] bf16
    const unsigned short* __restrict__ Bt,   // [OUT_F][IN_F] bf16 (W^T)
    const float* __restrict__ bias,          // [OUT_F]
    float* __restrict__ C)                   // [ROWS][OUT_F] fp32
{
  __shared__ __align__(16) unsigned short As[2][BM][BK];
  __shared__ __align__(16) unsigned short Bs[2][BN][BK];

  const int t    = threadIdx.x;
  const int lane = t & 63;
  const int wid  = t >> 6;
  const int wr   = wid >> 1;   // 2x2 wave grid, each wave owns 64x64
  const int wc   = wid & 1;

  // XCD-bijective swizzle (nwg=2048, %8==0). Decode bm fast so each XCD keeps a
  // 4-panel (4*128 cols x 4096 k x 2B = 4MB) slice of Bt resident in its L2.
  const int nwg = gridDim.x;
  const int bid = blockIdx.x;
  const int swz = (bid & 7) * (nwg >> 3) + (bid >> 3);
  const int bm  = swz & 63;
  const int bn  = swz >> 6;
  const int m0  = bm * BM;
  const int n0  = bn * BN;

  // lane-linear staging: thread t covers bytes [t*16, t*16+16) of each 4KB chunk;
  // 2 chunks per 8KB tile. row = chunk*64 + t/4, col = (t%4)*8 bf16.
  const unsigned short* gA = A  + (size_t)(m0 + (t >> 2)) * IN_F + (t & 3) * 8;
  const unsigned short* gB = Bt + (size_t)(n0 + (t >> 2)) * IN_F + (t & 3) * 8;
  unsigned short* lA = &As[0][0][0] + t * 8;
  unsigned short* lB = &Bs[0][0][0] + t * 8;

  f32x4 acc[4][4];
  #pragma unroll
  for (int i = 0; i < 4; ++i)
    #pragma unroll
    for (int j = 0; j < 4; ++j)
      acc[i][j] = (f32x4){0.f, 0.f, 0.f, 0.f};

  // prologue: stage k-tile 0 into buf 0
  GLD(gA, lA); GLD(gA + 64 * IN_F, lA + 2048);
  GLD(gB, lB); GLD(gB + 64 * IN_F, lB + 2048);
  __syncthreads();   // drains vmcnt(0) before barrier

  const int r15 = lane & 15;
  const int kg8 = (lane >> 4) * 8;
  int cur = 0;

  for (int kt = 0; kt < NKSTEP; ++kt) {
    if (kt + 1 < NKSTEP) {   // async prefetch of next k-tile into the other buffer
      const int ko = (kt + 1) * BK;
      const unsigned short* ga = gA + ko;
      const unsigned short* gb = gB + ko;
      unsigned short* la = lA + (cur ^ 1) * (BM * BK);
      unsigned short* lb = lB + (cur ^ 1) * (BN * BK);
      GLD(ga, la); GLD(ga + 64 * IN_F, la + 2048);
      GLD(gb, lb); GLD(gb + 64 * IN_F, lb + 2048);
    }
    const unsigned short* Ab = &As[cur][0][0];
    const unsigned short* Bb = &Bs[cur][0][0];
    bf16x8 af[4], bfv[4];
    #pragma unroll
    for (int mi = 0; mi < 4; ++mi)   // A frag: row = lane&15 (+16*mi), k = (lane>>4)*8..+7
      af[mi] = *(const bf16x8*)(Ab + (size_t)(wr * 64 + mi * 16 + r15) * BK + kg8);
    #pragma unroll
    for (int ni = 0; ni < 4; ++ni)   // B frag from Wt: col = lane&15, same k slice
      bfv[ni] = *(const bf16x8*)(Bb + (size_t)(wc * 64 + ni * 16 + r15) * BK + kg8);
    #pragma unroll
    for (int mi = 0; mi < 4; ++mi)
      #pragma unroll
      for (int ni = 0; ni < 4; ++ni)
        acc[mi][ni] = __builtin_amdgcn_mfma_f32_16x16x32_bf16(af[mi], bfv[ni], acc[mi][ni], 0, 0, 0);
    __syncthreads();
    cur ^= 1;
  }

  // epilogue: C/D layout col = lane&15, row = (lane>>4)*4 + reg
  float bv[4];
  #pragma unroll
  for (int ni = 0; ni < 4; ++ni)
    bv[ni] = bias[n0 + wc * 64 + ni * 16 + r15];

  const int rq4 = (lane >> 4) * 4;
  #pragma unroll
  for (int mi = 0; mi < 4; ++mi) {
    const int rbase = m0 + wr * 64 + mi * 16 + rq4;
    #pragma unroll
    for (int ni = 0; ni < 4; ++ni) {
      const int col = n0 + wc * 64 + ni * 16 + r15;
      #pragma unroll
      for (int r = 0; r < 4; ++r)
        C[(size_t)(rbase + r) * OUT_F + col] = acc[mi][ni][r] + bv[ni];
    }
  }
}

// ---------------- fallback (only if ws_size too small): correct, slow, no workspace ----------------
__global__ void qnaive_kernel(const float* __restrict__ x,
                              const float* __restrict__ rw, const float* __restrict__ iw,
                              const float* __restrict__ jw, const float* __restrict__ kw,
                              const float* __restrict__ bias, float* __restrict__ out) {
  const size_t idx = (size_t)blockIdx.x * 256 + threadIdx.x;
  const int m = (int)(idx >> 12);
  const int n = (int)(idx & 4095);
  const int cq = n >> 10, nq = n & 1023;
  const int   it[16] = {0,1,2,3, 1,0,3,2, 2,3,0,1, 3,2,1,0};
  const float st[16] = { 1.f, 1.f, 1.f, 1.f,
                        -1.f, 1.f, 1.f,-1.f,
                        -1.f,-1.f, 1.f, 1.f,
                        -1.f, 1.f,-1.f, 1.f};
  const float* srcs[4] = {rw, iw, jw, kw};
  float acc = 0.f;
  for (int rq = 0; rq < 4; ++rq) {
    const float* w  = srcs[it[rq * 4 + cq]];
    const float* xp = x + (size_t)m * IN_F + rq * 1024;
    float a = 0.f;
    for (int k = 0; k < 1024; ++k)
      a += xp[k] * w[(size_t)k * QDIM + nq];
    acc += st[rq * 4 + cq] * a;
  }
  out[idx] = acc + bias[n];
}

extern "C" void kernel_launch(void* const* d_in, const int* in_sizes, int n_in,
                              void* d_out, int out_size, void* d_ws, size_t ws_size,
                              hipStream_t stream) {
  const float* x  = (const float*)d_in[0];
  const float* rw = (const float*)d_in[1];
  const float* iw = (const float*)d_in[2];
  const float* jw = (const float*)d_in[3];
  const float* kw = (const float*)d_in[4];
  const float* b  = (const float*)d_in[5];
  float* out = (float*)d_out;

  const size_t xb_bytes = (size_t)ROWS * IN_F * 2;     // 64 MiB
  const size_t wt_bytes = (size_t)OUT_F * IN_F * 2;    // 32 MiB

  if (ws_size >= xb_bytes + wt_bytes) {
    unsigned short* xb = (unsigned short*)d_ws;
    unsigned short* wt = (unsigned short*)((char*)d_ws + xb_bytes);
    cvt_x_kernel<<<(ROWS * IN_F) / 2048, 256, 0, stream>>>(x, xb);
    build_wt_kernel<<<(OUT_F / 64) * (IN_F / 64), 256, 0, stream>>>(rw, iw, jw, kw, wt);
    qgemm_kernel<<<(ROWS / BM) * (OUT_F / BN), 256, 0, stream>>>(xb, wt, b, out);
  } else {
    qnaive_kernel<<<(int)(((size_t)ROWS * OUT_F) / 256), 256, 0, stream>>>(x, rw, iw, jw, kw, b, out);
  }
}

// Round 3
// 483.667 us; speedup vs baseline: 1.2520x; 1.2520x over previous
//
#include <hip/hip_runtime.h>
#include <stdint.h>

#define IN_F  4096
#define OUT_F 4096
#define ROWS  8192
#define QDIM  1024

typedef __attribute__((ext_vector_type(8))) short bf16x8;
typedef __attribute__((ext_vector_type(4))) float f32x4;
typedef __attribute__((ext_vector_type(8))) unsigned short u16x8;
typedef unsigned short ushort_t;

__device__ __forceinline__ unsigned short f2bf(float f) {
  union { float f; unsigned int u; } v; v.f = f;
  unsigned int u = v.u;
  u += 0x7FFFu + ((u >> 16) & 1u);
  return (unsigned short)(u >> 16);
}

// ---------------- prepass 1: x fp32 -> bf16 ----------------
__global__ void cvt_x_kernel(const float* __restrict__ x, ushort_t* __restrict__ xb) {
  const size_t t = (size_t)blockIdx.x * 256 + threadIdx.x;
  const float4* x4 = reinterpret_cast<const float4*>(x);
  float4 a = x4[2 * t];
  float4 b = x4[2 * t + 1];
  u16x8 o;
  o[0] = f2bf(a.x); o[1] = f2bf(a.y); o[2] = f2bf(a.z); o[3] = f2bf(a.w);
  o[4] = f2bf(b.x); o[5] = f2bf(b.y); o[6] = f2bf(b.z); o[7] = f2bf(b.w);
  *reinterpret_cast<u16x8*>(xb + 8 * t) = o;
}

// ---------------- prepass 2: build Wt (bf16, [n][k] = W^T), signs folded ----------------
__global__ void build_wt_kernel(const float* __restrict__ rw, const float* __restrict__ iw,
                                const float* __restrict__ jw, const float* __restrict__ kw,
                                ushort_t* __restrict__ wt) {
  __shared__ float tile[64][65];
  const int bid = blockIdx.x;
  const int tn = bid >> 6, tk = bid & 63;
  const int n0 = tn << 6, k0 = tk << 6;
  const int cq = n0 >> 10, rq = k0 >> 10;
  const int   it[16] = {0,1,2,3, 1,0,3,2, 2,3,0,1, 3,2,1,0};
  const float st[16] = { 1.f, 1.f, 1.f, 1.f,
                        -1.f, 1.f, 1.f,-1.f,
                        -1.f,-1.f, 1.f, 1.f,
                        -1.f, 1.f,-1.f, 1.f};
  const float* srcs[4] = {rw, iw, jw, kw};
  const float* src = srcs[it[rq * 4 + cq]];
  const float sgn  = st[rq * 4 + cq];
  const int tid = threadIdx.x;
  const int tx = tid & 63, ty = tid >> 6;
  const int ks = k0 & 1023, ns = n0 & 1023;
  #pragma unroll
  for (int r = ty; r < 64; r += 4)
    tile[r][tx] = src[(size_t)(ks + r) * QDIM + ns + tx] * sgn;
  __syncthreads();
  const int k8 = (tid & 7) * 8;
  #pragma unroll
  for (int pass = 0; pass < 2; ++pass) {
    const int nr = (tid >> 3) + pass * 32;
    u16x8 o;
    #pragma unroll
    for (int j = 0; j < 8; ++j) o[j] = f2bf(tile[k8 + j][nr]);
    *reinterpret_cast<u16x8*>(wt + (size_t)(n0 + nr) * IN_F + k0 + k8) = o;
  }
}

// ---------------- 8-phase 256x256 GEMM: C = A(bf16) * Wt(bf16)^T + bias ----------------
// BM=BN=256, BK=64, 512 thr (8 waves: wr=wid>>2 in 0..1, wc=wid&3 in 0..3).
// Wave rows: mi*32+wr*16 (mi 0..7)  -> A halves 0 (mi<4) / 1 (mi>=4)
// Wave cols: ni*64+wc*16 (ni 0..3)  -> B halves 0 (ni<2) / 1 (ni>=2)
// LDS linear per half [128][64], staged by global_load_lds with PRE-SWIZZLED global
// source (kbyte ^= (row&7)<<4); frag reads apply the same XOR -> conflict-free.
#define NT 64                       // K / BK
#define BUFS 32768                  // ushorts per buffer (2 mats x 2 halves x 8192)

#define GLD(g, l) __builtin_amdgcn_global_load_lds(                         \
    (const __attribute__((address_space(1))) void*)(g),                     \
    (__attribute__((address_space(3))) void*)(l), 16, 0, 0)

// stage order slot SO -> (mat, half): 0=(A,0) 1=(B,1) 2=(A,1) 3=(B,0)
#define STAGE(SO, TILE) do {                                                \
  if ((TILE) < NT) {                                                        \
    const int mat_  = ((SO) & 1);                                           \
    const int half_ = ((SO) == 1 || (SO) == 2);                             \
    const ushort_t* g_ = (mat_ ? srcB : srcA)                               \
        + (size_t)(half_ * 128) * IN_F + (size_t)(TILE) * 64;               \
    ushort_t* l_ = ldst + ((TILE) & 1) * BUFS + mat_ * 16384 + half_ * 8192;\
    GLD(g_, l_); GLD(g_ + (size_t)64 * IN_F, l_ + 4096);                    \
  }                                                                         \
} while (0)

#define READ_A(AH) do { const ushort_t* ab_ = smb + (AH) * 8192;            \
  _Pragma("unroll") for (int mi = 0; mi < 4; ++mi)                          \
    _Pragma("unroll") for (int ks = 0; ks < 2; ++ks)                        \
      af[mi][ks] = *(const bf16x8*)(ab_ + aoff[mi][ks]); } while (0)

#define READ_B(BH) do { const ushort_t* bb_ = smb + 16384 + (BH) * 8192;    \
  _Pragma("unroll") for (int ni = 0; ni < 2; ++ni)                          \
    _Pragma("unroll") for (int ks = 0; ks < 2; ++ks)                        \
      bfr[ni][ks] = *(const bf16x8*)(bb_ + boff[ni][ks]); } while (0)

#define MFMA16(AH, BH)                                                      \
  _Pragma("unroll") for (int ks = 0; ks < 2; ++ks)                          \
    _Pragma("unroll") for (int mi = 0; mi < 4; ++mi)                        \
      _Pragma("unroll") for (int ni = 0; ni < 2; ++ni)                      \
        acc[(AH)*4+mi][(BH)*2+ni] = __builtin_amdgcn_mfma_f32_16x16x32_bf16(\
            af[mi][ks], bfr[ni][ks], acc[(AH)*4+mi][(BH)*2+ni], 0, 0, 0)

#define NOVM ((void)0)
#define VM6 asm volatile("s_waitcnt vmcnt(6)" ::: "memory")
#define VM0 asm volatile("s_waitcnt vmcnt(0)" ::: "memory")

#define PHASE(RA, RB, AH, BH, SO, STILE, VMW) do {                          \
  if (RA) READ_A(AH);                                                       \
  if (RB) READ_B(BH);                                                       \
  STAGE(SO, STILE);                                                         \
  __builtin_amdgcn_s_barrier();                                             \
  asm volatile("s_waitcnt lgkmcnt(0)" ::: "memory");                        \
  __builtin_amdgcn_sched_barrier(0);                                        \
  __builtin_amdgcn_s_setprio(1);                                            \
  MFMA16(AH, BH);                                                           \
  __builtin_amdgcn_s_setprio(0);                                            \
  __builtin_amdgcn_sched_barrier(0);                                        \
  VMW;                                                                      \
  __builtin_amdgcn_s_barrier();                                             \
} while (0)

// quadrants (0,0),(0,1),(1,1),(1,0); stage slots lead 3 half-tiles past block end
#define BLOCK(T, VMW) do {                                                  \
  const ushort_t* smb = lds0 + ((T) & 1) * BUFS;                            \
  PHASE(1, 1, 0, 0, 3, (T) + 1, NOVM);                                      \
  PHASE(0, 1, 0, 1, 0, (T) + 2, NOVM);                                      \
  PHASE(1, 0, 1, 1, 1, (T) + 2, NOVM);                                      \
  PHASE(0, 1, 1, 0, 2, (T) + 2, VMW);                                       \
} while (0)

__global__ __launch_bounds__(512, 2) void qgemm8_kernel(
    const ushort_t* __restrict__ A,    // [ROWS][IN_F] bf16
    const ushort_t* __restrict__ Bt,   // [OUT_F][IN_F] bf16
    const float* __restrict__ bias,
    float* __restrict__ C) {
  __shared__ ushort_t sm[2][2][2][128][64];   // 128 KiB

  const int tid  = threadIdx.x;
  const int lane = tid & 63;
  const int wid  = tid >> 6;
  const int wr   = wid >> 2;
  const int wc   = wid & 3;
  const int r15  = lane & 15;
  const int kg   = lane >> 4;
  const int sw   = (r15 & 7) << 4;       // byte swizzle within 128B row

  // XCD-bijective swizzle (nwg=512): B-panel pair stays L2-resident per XCD
  const int bid = blockIdx.x;
  const int swz = (bid & 7) * 64 + (bid >> 3);
  const int bm  = swz & 31;
  const int bn  = swz >> 5;
  const int m0  = bm * 256;
  const int n0  = bn * 256;

  // staging bases (pre-swizzled global k so LDS stays linear)
  const int srow = tid >> 3;
  const int skel = 8 * ((tid & 7) ^ (srow & 7));
  const ushort_t* srcA = A  + (size_t)(m0 + srow) * IN_F + skel;
  const ushort_t* srcB = Bt + (size_t)(n0 + srow) * IN_F + skel;
  ushort_t* lds0 = &sm[0][0][0][0][0];
  ushort_t* ldst = lds0 + tid * 8;

  // fragment read offsets (ushort units), swizzled
  int aoff[4][2], boff[2][2];
  #pragma unroll
  for (int mi = 0; mi < 4; ++mi)
    #pragma unroll
    for (int ks = 0; ks < 2; ++ks)
      aoff[mi][ks] = (mi * 32 + wr * 16 + r15) * 64 + (((ks * 64 + kg * 16) ^ sw) >> 1);
  #pragma unroll
  for (int ni = 0; ni < 2; ++ni)
    #pragma unroll
    for (int ks = 0; ks < 2; ++ks)
      boff[ni][ks] = (ni * 64 + wc * 16 + r15) * 64 + (((ks * 64 + kg * 16) ^ sw) >> 1);

  f32x4 acc[8][4];
  #pragma unroll
  for (int i = 0; i < 8; ++i)
    #pragma unroll
    for (int j = 0; j < 4; ++j)
      acc[i][j] = (f32x4){0.f, 0.f, 0.f, 0.f};

  bf16x8 af[4][2], bfr[2][2];

  // prologue: tile0 fully + 3 half-tiles of tile1 in flight
  STAGE(0, 0); STAGE(1, 0); STAGE(2, 0); STAGE(3, 0);
  STAGE(0, 1); STAGE(1, 1); STAGE(2, 1);
  VM6;
  __builtin_amdgcn_s_barrier();

  for (int t = 0; t < NT - 2; ++t) BLOCK(t, VM6);
  BLOCK(NT - 2, VM0);
  BLOCK(NT - 1, NOVM);

  // epilogue: C/D map col = lane&15, row = (lane>>4)*4 + reg
  float bv[4];
  #pragma unroll
  for (int ni = 0; ni < 4; ++ni)
    bv[ni] = bias[n0 + ni * 64 + wc * 16 + r15];
  const int rq4 = (lane >> 4) * 4;
  #pragma unroll
  for (int mi = 0; mi < 8; ++mi) {
    const int rbase = m0 + mi * 32 + wr * 16 + rq4;
    #pragma unroll
    for (int ni = 0; ni < 4; ++ni) {
      const int col = n0 + ni * 64 + wc * 16 + r15;
      #pragma unroll
      for (int r = 0; r < 4; ++r)
        C[(size_t)(rbase + r) * OUT_F + col] = acc[mi][ni][r] + bv[ni];
    }
  }
}

// ---------------- fallback: correct, slow, no workspace ----------------
__global__ void qnaive_kernel(const float* __restrict__ x,
                              const float* __restrict__ rw, const float* __restrict__ iw,
                              const float* __restrict__ jw, const float* __restrict__ kw,
                              const float* __restrict__ bias, float* __restrict__ out) {
  const size_t idx = (size_t)blockIdx.x * 256 + threadIdx.x;
  const int m = (int)(idx >> 12);
  const int n = (int)(idx & 4095);
  const int cq = n >> 10, nq = n & 1023;
  const int   it[16] = {0,1,2,3, 1,0,3,2, 2,3,0,1, 3,2,1,0};
  const float st[16] = { 1.f, 1.f, 1.f, 1.f,
                        -1.f, 1.f, 1.f,-1.f,
                        -1.f,-1.f, 1.f, 1.f,
                        -1.f, 1.f,-1.f, 1.f};
  const float* srcs[4] = {rw, iw, jw, kw};
  float acc = 0.f;
  for (int rq = 0; rq < 4; ++rq) {
    const float* w  = srcs[it[rq * 4 + cq]];
    const float* xp = x + (size_t)m * IN_F + rq * 1024;
    float a = 0.f;
    for (int k = 0; k < 1024; ++k)
      a += xp[k] * w[(size_t)k * QDIM + nq];
    acc += st[rq * 4 + cq] * a;
  }
  out[idx] = acc + bias[n];
}

extern "C" void kernel_launch(void* const* d_in, const int* in_sizes, int n_in,
                              void* d_out, int out_size, void* d_ws, size_t ws_size,
                              hipStream_t stream) {
  const float* x  = (const float*)d_in[0];
  const float* rw = (const float*)d_in[1];
  const float* iw = (const float*)d_in[2];
  const float* jw = (const float*)d_in[3];
  const float* kw = (const float*)d_in[4];
  const float* b  = (const float*)d_in[5];
  float* out = (float*)d_out;

  const size_t xb_bytes = (size_t)ROWS * IN_F * 2;
  const size_t wt_bytes = (size_t)OUT_F * IN_F * 2;

  if (ws_size >= xb_bytes + wt_bytes) {
    ushort_t* xb = (ushort_t*)d_ws;
    ushort_t* wt = (ushort_t*)((char*)d_ws + xb_bytes);
    cvt_x_kernel<<<(ROWS * IN_F) / 2048, 256, 0, stream>>>(x, xb);
    build_wt_kernel<<<(OUT_F / 64) * (IN_F / 64), 256, 0, stream>>>(rw, iw, jw, kw, wt);
    qgemm8_kernel<<<(ROWS / 256) * (OUT_F / 256), 512, 0, stream>>>(xb, wt, b, out);
  } else {
    qnaive_kernel<<<(int)(((size_t)ROWS * OUT_F) / 256), 256, 0, stream>>>(x, rw, iw, jw, kw, b, out);
  }
}